// Round 1
// baseline (568.258 us; speedup 1.0000x reference)
//
#include <hip/hip_runtime.h>
#include <stdint.h>

#define NANCH 138240      // 15 * 96 * 96
#define B_CNT 32
#define PRE 1024
#define POST 256
#define BINS 8192         // 13-bit prefix histogram
#define CAP 4096          // candidate cap (expected ~1.2k)

// ---- score: log_softmax over 2 classes, value = logp[class=1] -------------
__device__ __forceinline__ float score_at(const float* __restrict__ cb, int idx) {
    float x0 = cb[idx];
    float x1 = cb[idx + NANCH];
    float m  = fmaxf(x0, x1);
    float e0 = expf(x0 - m);
    float e1 = expf(x1 - m);
    return (x1 - m) - logf(e0 + e1);
}

// descending-score sortable key (ascending uint = descending score)
__device__ __forceinline__ unsigned key32(float sc) {
    unsigned u = __float_as_uint(sc);
    unsigned s = (u & 0x80000000u) ? ~u : (u | 0x80000000u);
    return ~s;
}

// ---- box decode (no FMA contraction; matches numpy fp32 op-for-op) --------
__device__ __forceinline__ void decode_box(const float* __restrict__ reg,
                                           const float* __restrict__ anch,
                                           int b, int idx, float box[4]) {
    const float* rb = reg + (size_t)b * 4 * NANCH;
    float dx = rb[idx];
    float dy = rb[idx + NANCH];
    float dw = rb[idx + 2 * NANCH];
    float dh = rb[idx + 3 * NANCH];
    float ax1 = anch[idx * 4 + 0], ay1 = anch[idx * 4 + 1];
    float ax2 = anch[idx * 4 + 2], ay2 = anch[idx * 4 + 3];
    float aw  = __fadd_rn(__fsub_rn(ax2, ax1), 1.0f);
    float ah  = __fadd_rn(__fsub_rn(ay2, ay1), 1.0f);
    float acx = __fadd_rn(ax1, __fmul_rn(0.5f, aw));
    float acy = __fadd_rn(ay1, __fmul_rn(0.5f, ah));
    float pcx = __fadd_rn(__fmul_rn(dx, aw), acx);
    float pcy = __fadd_rn(__fmul_rn(dy, ah), acy);
    float pw  = __fmul_rn(expf(dw), aw);
    float ph  = __fmul_rn(expf(dh), ah);
    float hx  = __fmul_rn(0.5f, pw);
    float hy  = __fmul_rn(0.5f, ph);
    box[0] = fminf(fmaxf(__fsub_rn(pcx, hx), 0.0f), 767.0f);
    box[1] = fminf(fmaxf(__fsub_rn(pcy, hy), 0.0f), 767.0f);
    box[2] = fminf(fmaxf(__fadd_rn(pcx, hx), 0.0f), 767.0f);
    box[3] = fminf(fmaxf(__fadd_rn(pcy, hy), 0.0f), 767.0f);
}

// ---- kernel 1: per-batch top-1024 select (hist -> compact -> bitonic) -----
__global__ __launch_bounds__(1024) void sel_kernel(const float* __restrict__ cls,
                                                   const float* __restrict__ reg,
                                                   const float* __restrict__ anch,
                                                   float* __restrict__ topS,
                                                   float* __restrict__ topB) {
    __shared__ unsigned long long s_keys[CAP];   // 32 KB; aliased as 8192-bin hist
    __shared__ unsigned s_part[1024];
    __shared__ int s_bstar;
    __shared__ int s_count;
    const int b = blockIdx.x;
    const int t = threadIdx.x;
    const float* cb = cls + (size_t)b * 2 * NANCH;
    unsigned* hist = (unsigned*)s_keys;          // 8192 u32 == 4096 u64

    for (int i = t; i < BINS; i += 1024) hist[i] = 0;
    __syncthreads();

    // pass 1: histogram of 13-bit key prefix
    for (int idx = t; idx < NANCH; idx += 1024) {
        unsigned k = key32(score_at(cb, idx)) >> 19;
        atomicAdd(&hist[k], 1u);
    }
    __syncthreads();

    // segment sums (8 bins/thread) + inclusive scan over 1024 segments
    unsigned seg = 0;
    for (int i = 0; i < 8; i++) seg += hist[t * 8 + i];
    s_part[t] = seg;
    __syncthreads();
    for (int off = 1; off < 1024; off <<= 1) {
        unsigned v = (t >= off) ? s_part[t - off] : 0u;
        __syncthreads();
        s_part[t] += v;
        __syncthreads();
    }
    unsigned incl = s_part[t];
    unsigned excl = (t == 0) ? 0u : s_part[t - 1];
    if (incl >= PRE && excl < PRE) {         // unique crossing segment
        unsigned cum = excl;
        int bstar = t * 8 + 7;
        for (int i = 0; i < 8; i++) {
            unsigned c = hist[t * 8 + i];
            if (cum + c >= PRE) { bstar = t * 8 + i; break; }
            cum += c;
        }
        s_bstar = bstar;
        s_count = 0;
    }
    __syncthreads();
    const int bstar = s_bstar;

    // pass 2: compact candidates (prefix <= bstar) as 64-bit keys
    for (int idx = t; idx < NANCH; idx += 1024) {
        unsigned k = key32(score_at(cb, idx));
        if ((int)(k >> 19) <= bstar) {
            int pos = atomicAdd(&s_count, 1);
            if (pos < CAP)
                s_keys[pos] = ((unsigned long long)k << 32) | (unsigned)idx;
        }
    }
    __syncthreads();
    int cnt = s_count; if (cnt > CAP) cnt = CAP;
    for (int i = cnt + t; i < CAP; i += 1024) s_keys[i] = 0xFFFFFFFFFFFFFFFFull;
    __syncthreads();

    // bitonic sort ascending (keys are distinct: idx baked into low bits)
    for (int k = 2; k <= CAP; k <<= 1) {
        for (int j = k >> 1; j > 0; j >>= 1) {
            for (int i = t; i < CAP; i += 1024) {
                int ixj = i ^ j;
                if (ixj > i) {
                    bool up = ((i & k) == 0);
                    unsigned long long a = s_keys[i], c = s_keys[ixj];
                    if ((a > c) == up) { s_keys[i] = c; s_keys[ixj] = a; }
                }
            }
            __syncthreads();
        }
    }

    // emit top-1024: recover score bits, decode box
    if (t < PRE) {
        unsigned long long key = s_keys[t];
        int idx = (int)(key & 0xFFFFFFFFu);
        unsigned ks = (unsigned)(key >> 32);
        unsigned s  = ~ks;
        unsigned u  = (s & 0x80000000u) ? (s & 0x7FFFFFFFu) : ~s;
        float sc = __uint_as_float(u);
        float box[4];
        decode_box(reg, anch, b, idx, box);
        topS[b * PRE + t] = sc;
        float* tb = topB + ((size_t)b * PRE + t) * 4;
        tb[0] = box[0]; tb[1] = box[1]; tb[2] = box[2]; tb[3] = box[3];
    }
}

// ---- kernel 2: suppression bitmask (iou > 0.7 for j > i) ------------------
__global__ __launch_bounds__(1024) void mask_kernel(const float* __restrict__ topB,
                                                    unsigned long long* __restrict__ masks) {
    const int w = blockIdx.x;   // 64-col chunk: 0..15
    const int b = blockIdx.y;
    const int i = threadIdx.x;  // row 0..1023
    __shared__ float sx1[64], sy1[64], sx2[64], sy2[64], sar[64];
    if (i < 64) {
        const float* p = topB + ((size_t)b * PRE + w * 64 + i) * 4;
        float x1 = p[0], y1 = p[1], x2 = p[2], y2 = p[3];
        sx1[i] = x1; sy1[i] = y1; sx2[i] = x2; sy2[i] = y2;
        sar[i] = __fmul_rn(__fadd_rn(__fsub_rn(x2, x1), 1.0f),
                           __fadd_rn(__fsub_rn(y2, y1), 1.0f));
    }
    __syncthreads();
    const float* p = topB + ((size_t)b * PRE + i) * 4;
    float x1 = p[0], y1 = p[1], x2 = p[2], y2 = p[3];
    float ar = __fmul_rn(__fadd_rn(__fsub_rn(x2, x1), 1.0f),
                         __fadd_rn(__fsub_rn(y2, y1), 1.0f));
    unsigned long long m = 0ull;
    const int jbase = w * 64;
    for (int j = 0; j < 64; j++) {
        int jj = jbase + j;
        if (jj > i) {
            float ix1 = fmaxf(x1, sx1[j]);
            float iy1 = fmaxf(y1, sy1[j]);
            float ix2 = fminf(x2, sx2[j]);
            float iy2 = fminf(y2, sy2[j]);
            float iw = fmaxf(__fadd_rn(__fsub_rn(ix2, ix1), 1.0f), 0.0f);
            float ih = fmaxf(__fadd_rn(__fsub_rn(iy2, iy1), 1.0f), 0.0f);
            float inter = __fmul_rn(iw, ih);
            float denom = __fsub_rn(__fadd_rn(ar, sar[j]), inter);
            float iou = __fdiv_rn(inter, denom);
            if (iou > 0.7f) m |= (1ull << j);
        }
    }
    masks[((size_t)b * PRE + i) * 16 + w] = m;
}

// ---- kernel 3: serial greedy scan over bitmasks + emit --------------------
__global__ __launch_bounds__(64) void nms_kernel(const unsigned long long* __restrict__ masks,
                                                 const float* __restrict__ topS,
                                                 const float* __restrict__ topB,
                                                 float* __restrict__ out) {
    const int b = blockIdx.x;
    const int t = threadIdx.x;  // 64 threads; lanes 0..15 own removed-words
    __shared__ int kept[POST];
    __shared__ int s_nk;
    unsigned long long removed = 0ull;
    int nk = 0;
    for (int i = 0; i < PRE; i++) {
        unsigned long long rw = __shfl(removed, i >> 6);
        bool keep = !((rw >> (i & 63)) & 1ull);
        if (keep) {
            if (t < 16) removed |= masks[((size_t)b * PRE + i) * 16 + t];
            if (t == 0 && nk < POST) kept[nk] = i;
            nk++;
        }
    }
    if (t == 0) s_nk = (nk < POST) ? nk : POST;
    __syncthreads();
    const int n = s_nk;
    float* ob = out + (size_t)b * POST * 5;
    for (int r = t; r < POST; r += 64) {
        if (r < n) {
            int i = kept[r];
            ob[r * 5 + 0] = topS[b * PRE + i];
            const float* tb = topB + ((size_t)b * PRE + i) * 4;
            ob[r * 5 + 1] = tb[0];
            ob[r * 5 + 2] = tb[1];
            ob[r * 5 + 3] = tb[2];
            ob[r * 5 + 4] = tb[3];
        } else {
            ob[r * 5 + 0] = 0.0f; ob[r * 5 + 1] = 0.0f; ob[r * 5 + 2] = 0.0f;
            ob[r * 5 + 3] = 0.0f; ob[r * 5 + 4] = 0.0f;
        }
    }
}

extern "C" void kernel_launch(void* const* d_in, const int* in_sizes, int n_in,
                              void* d_out, int out_size, void* d_ws, size_t ws_size,
                              hipStream_t stream) {
    const float* cls  = (const float*)d_in[0];
    const float* reg  = (const float*)d_in[1];
    const float* anch = (const float*)d_in[2];
    float* topS = (float*)d_ws;                              // 32*1024 f32
    float* topB = topS + B_CNT * PRE;                        // 32*1024*4 f32
    unsigned long long* masks =
        (unsigned long long*)(topB + (size_t)B_CNT * PRE * 4);  // 32*1024*16 u64

    sel_kernel<<<B_CNT, 1024, 0, stream>>>(cls, reg, anch, topS, topB);
    mask_kernel<<<dim3(16, B_CNT), 1024, 0, stream>>>(topB, masks);
    nms_kernel<<<B_CNT, 64, 0, stream>>>(masks, topS, topB, (float*)d_out);
}

// Round 2
// 275.872 us; speedup vs baseline: 2.0599x; 2.0599x over previous
//
#include <hip/hip_runtime.h>
#include <stdint.h>

#define NANCH 138240      // 15 * 96 * 96
#define B_CNT 32
#define PRE 1024
#define POST 256
#define BINS 8192         // 13-bit prefix histogram
#define CAP 4096          // candidate cap (expected ~1.2k)

typedef unsigned long long u64;

// ---- score: log_softmax over 2 classes, value = logp[class=1] -------------
__device__ __forceinline__ float score_at(const float* __restrict__ cb, int idx) {
    float x0 = cb[idx];
    float x1 = cb[idx + NANCH];
    float m  = fmaxf(x0, x1);
    float e0 = expf(x0 - m);
    float e1 = expf(x1 - m);
    return (x1 - m) - logf(e0 + e1);
}

// descending-score sortable key (ascending uint = descending score)
__device__ __forceinline__ unsigned key32(float sc) {
    unsigned u = __float_as_uint(sc);
    unsigned s = (u & 0x80000000u) ? ~u : (u | 0x80000000u);
    return ~s;
}

// ---- box decode (no FMA contraction; matches numpy fp32 op-for-op) --------
__device__ __forceinline__ void decode_box(const float* __restrict__ reg,
                                           const float* __restrict__ anch,
                                           int b, int idx, float box[4]) {
    const float* rb = reg + (size_t)b * 4 * NANCH;
    float dx = rb[idx];
    float dy = rb[idx + NANCH];
    float dw = rb[idx + 2 * NANCH];
    float dh = rb[idx + 3 * NANCH];
    float ax1 = anch[idx * 4 + 0], ay1 = anch[idx * 4 + 1];
    float ax2 = anch[idx * 4 + 2], ay2 = anch[idx * 4 + 3];
    float aw  = __fadd_rn(__fsub_rn(ax2, ax1), 1.0f);
    float ah  = __fadd_rn(__fsub_rn(ay2, ay1), 1.0f);
    float acx = __fadd_rn(ax1, __fmul_rn(0.5f, aw));
    float acy = __fadd_rn(ay1, __fmul_rn(0.5f, ah));
    float pcx = __fadd_rn(__fmul_rn(dx, aw), acx);
    float pcy = __fadd_rn(__fmul_rn(dy, ah), acy);
    float pw  = __fmul_rn(expf(dw), aw);
    float ph  = __fmul_rn(expf(dh), ah);
    float hx  = __fmul_rn(0.5f, pw);
    float hy  = __fmul_rn(0.5f, ph);
    box[0] = fminf(fmaxf(__fsub_rn(pcx, hx), 0.0f), 767.0f);
    box[1] = fminf(fmaxf(__fsub_rn(pcy, hy), 0.0f), 767.0f);
    box[2] = fminf(fmaxf(__fadd_rn(pcx, hx), 0.0f), 767.0f);
    box[3] = fminf(fmaxf(__fadd_rn(pcy, hy), 0.0f), 767.0f);
}

// ---- kernel 1: per-batch top-1024 select (hist -> compact -> bitonic) -----
__global__ __launch_bounds__(1024) void sel_kernel(const float* __restrict__ cls,
                                                   const float* __restrict__ reg,
                                                   const float* __restrict__ anch,
                                                   float* __restrict__ topS,
                                                   float* __restrict__ topB) {
    __shared__ u64 s_keys[CAP];   // 32 KB; aliased as 8192-bin hist
    __shared__ unsigned s_part[1024];
    __shared__ int s_bstar;
    __shared__ int s_count;
    const int b = blockIdx.x;
    const int t = threadIdx.x;
    const float* cb = cls + (size_t)b * 2 * NANCH;
    unsigned* hist = (unsigned*)s_keys;          // 8192 u32 == 4096 u64

    for (int i = t; i < BINS; i += 1024) hist[i] = 0;
    __syncthreads();

    // pass 1: histogram of 13-bit key prefix
    for (int idx = t; idx < NANCH; idx += 1024) {
        unsigned k = key32(score_at(cb, idx)) >> 19;
        atomicAdd(&hist[k], 1u);
    }
    __syncthreads();

    // segment sums (8 bins/thread) + inclusive scan over 1024 segments
    unsigned seg = 0;
    for (int i = 0; i < 8; i++) seg += hist[t * 8 + i];
    s_part[t] = seg;
    __syncthreads();
    for (int off = 1; off < 1024; off <<= 1) {
        unsigned v = (t >= off) ? s_part[t - off] : 0u;
        __syncthreads();
        s_part[t] += v;
        __syncthreads();
    }
    unsigned incl = s_part[t];
    unsigned excl = (t == 0) ? 0u : s_part[t - 1];
    if (incl >= PRE && excl < PRE) {         // unique crossing segment
        unsigned cum = excl;
        int bstar = t * 8 + 7;
        for (int i = 0; i < 8; i++) {
            unsigned c = hist[t * 8 + i];
            if (cum + c >= PRE) { bstar = t * 8 + i; break; }
            cum += c;
        }
        s_bstar = bstar;
        s_count = 0;
    }
    __syncthreads();
    const int bstar = s_bstar;

    // pass 2: compact candidates (prefix <= bstar) as 64-bit keys
    for (int idx = t; idx < NANCH; idx += 1024) {
        unsigned k = key32(score_at(cb, idx));
        if ((int)(k >> 19) <= bstar) {
            int pos = atomicAdd(&s_count, 1);
            if (pos < CAP)
                s_keys[pos] = ((u64)k << 32) | (unsigned)idx;
        }
    }
    __syncthreads();
    int cnt = s_count; if (cnt > CAP) cnt = CAP;
    for (int i = cnt + t; i < CAP; i += 1024) s_keys[i] = 0xFFFFFFFFFFFFFFFFull;
    __syncthreads();

    // bitonic sort ascending (keys are distinct: idx baked into low bits)
    for (int k = 2; k <= CAP; k <<= 1) {
        for (int j = k >> 1; j > 0; j >>= 1) {
            for (int i = t; i < CAP; i += 1024) {
                int ixj = i ^ j;
                if (ixj > i) {
                    bool up = ((i & k) == 0);
                    u64 a = s_keys[i], c = s_keys[ixj];
                    if ((a > c) == up) { s_keys[i] = c; s_keys[ixj] = a; }
                }
            }
            __syncthreads();
        }
    }

    // emit top-1024: recover score bits, decode box
    if (t < PRE) {
        u64 key = s_keys[t];
        int idx = (int)(key & 0xFFFFFFFFu);
        unsigned ks = (unsigned)(key >> 32);
        unsigned s  = ~ks;
        unsigned u  = (s & 0x80000000u) ? (s & 0x7FFFFFFFu) : ~s;
        float sc = __uint_as_float(u);
        float box[4];
        decode_box(reg, anch, b, idx, box);
        topS[b * PRE + t] = sc;
        float* tb = topB + ((size_t)b * PRE + t) * 4;
        tb[0] = box[0]; tb[1] = box[1]; tb[2] = box[2]; tb[3] = box[3];
    }
}

// ---- kernel 2: suppression bitmask (iou > 0.7 for j > i) ------------------
__global__ __launch_bounds__(1024) void mask_kernel(const float* __restrict__ topB,
                                                    u64* __restrict__ masks) {
    const int w = blockIdx.x;   // 64-col chunk: 0..15
    const int b = blockIdx.y;
    const int i = threadIdx.x;  // row 0..1023
    __shared__ float sx1[64], sy1[64], sx2[64], sy2[64], sar[64];
    if (i < 64) {
        const float* p = topB + ((size_t)b * PRE + w * 64 + i) * 4;
        float x1 = p[0], y1 = p[1], x2 = p[2], y2 = p[3];
        sx1[i] = x1; sy1[i] = y1; sx2[i] = x2; sy2[i] = y2;
        sar[i] = __fmul_rn(__fadd_rn(__fsub_rn(x2, x1), 1.0f),
                           __fadd_rn(__fsub_rn(y2, y1), 1.0f));
    }
    __syncthreads();
    const float* p = topB + ((size_t)b * PRE + i) * 4;
    float x1 = p[0], y1 = p[1], x2 = p[2], y2 = p[3];
    float ar = __fmul_rn(__fadd_rn(__fsub_rn(x2, x1), 1.0f),
                         __fadd_rn(__fsub_rn(y2, y1), 1.0f));
    u64 m = 0ull;
    const int jbase = w * 64;
    for (int j = 0; j < 64; j++) {
        int jj = jbase + j;
        if (jj > i) {
            float ix1 = fmaxf(x1, sx1[j]);
            float iy1 = fmaxf(y1, sy1[j]);
            float ix2 = fminf(x2, sx2[j]);
            float iy2 = fminf(y2, sy2[j]);
            float iw = fmaxf(__fadd_rn(__fsub_rn(ix2, ix1), 1.0f), 0.0f);
            float ih = fmaxf(__fadd_rn(__fsub_rn(iy2, iy1), 1.0f), 0.0f);
            float inter = __fmul_rn(iw, ih);
            float denom = __fsub_rn(__fadd_rn(ar, sar[j]), inter);
            float iou = __fdiv_rn(inter, denom);
            if (iou > 0.7f) m |= (1ull << j);
        }
    }
    masks[((size_t)b * PRE + i) * 16 + w] = m;
}

// ---- 64-bit helpers over wave --------------------------------------------
__device__ __forceinline__ u64 shfl_xor_u64(u64 v, int lanemask) {
    int lo = __shfl_xor((int)(v & 0xFFFFFFFFull), lanemask);
    int hi = __shfl_xor((int)(v >> 32), lanemask);
    return ((u64)(unsigned)hi << 32) | (unsigned)lo;
}

// ---- kernel 3: chunked wave-parallel greedy NMS ---------------------------
// One wave per batch. 16 chunks of 64 rows. Intra-chunk: serial 64-step
// register-only recurrence (readlane). Cross-chunk: preloaded mask words,
// OR-reduce of kept rows, accumulated into LDS rem[16].
__global__ __launch_bounds__(64) void nms_kernel(const u64* __restrict__ masks,
                                                 const float* __restrict__ topS,
                                                 const float* __restrict__ topB,
                                                 float* __restrict__ out) {
    const int b = blockIdx.x;
    const int t = threadIdx.x;      // 0..63
    __shared__ u64 rem[16];
    __shared__ int kept[POST];
    __shared__ int s_nk;
    if (t < 16) rem[t] = 0ull;
    __syncthreads();

    const u64* mb = masks + (size_t)b * PRE * 16;
    const int w = t >> 2, g = t & 3;   // cross-chunk role: word w, row-group g
    int prefix = 0;

    for (int c = 0; c < 16; ++c) {
        // diagonal word for row c*64 + t (intra-chunk suppression bits)
        u64 dv = mb[((size_t)(c * 64 + t)) * 16 + c];
        int dlo = (int)(dv & 0xFFFFFFFFull);
        int dhi = (int)(dv >> 32);

        // preload cross-chunk words: lane (w,g) covers rows g*16..g*16+15, word w
        u64 cw[16];
        #pragma unroll
        for (int k = 0; k < 16; ++k)
            cw[k] = mb[((size_t)(c * 64 + g * 16 + k)) * 16 + w];

        u64 alive = ~rem[c];

        // serial greedy within chunk: register-only recurrence
        for (int l = 0; l < 64; ++l) {
            unsigned lo = (unsigned)__builtin_amdgcn_readlane(dlo, l);
            unsigned hi = (unsigned)__builtin_amdgcn_readlane(dhi, l);
            u64 dl = ((u64)hi << 32) | lo;
            u64 a = (alive >> l) & 1ull;
            alive &= ~(a ? dl : 0ull);
        }

        // record kept rows of this chunk (order = row order)
        if ((alive >> t) & 1ull) {
            int pos = prefix + (int)__popcll(alive & ((1ull << t) - 1ull));
            if (pos < POST) kept[pos] = c * 64 + t;
        }
        prefix += (int)__popcll(alive);

        // cross-chunk suppression: OR mask words of kept rows
        u64 acc = 0ull;
        #pragma unroll
        for (int k = 0; k < 16; ++k)
            if ((alive >> (g * 16 + k)) & 1ull) acc |= cw[k];
        acc |= shfl_xor_u64(acc, 1);
        acc |= shfl_xor_u64(acc, 2);
        __syncthreads();
        if (g == 0 && w > c) rem[w] |= acc;   // lane 4*w owns word w
        __syncthreads();
    }

    if (t == 0) s_nk = (prefix < POST) ? prefix : POST;
    __syncthreads();
    const int n = s_nk;

    float* ob = out + (size_t)b * POST * 5;
    for (int r = t; r < POST; r += 64) {
        if (r < n) {
            int i = kept[r];
            ob[r * 5 + 0] = topS[b * PRE + i];
            const float* tb = topB + ((size_t)b * PRE + i) * 4;
            ob[r * 5 + 1] = tb[0];
            ob[r * 5 + 2] = tb[1];
            ob[r * 5 + 3] = tb[2];
            ob[r * 5 + 4] = tb[3];
        } else {
            ob[r * 5 + 0] = 0.0f; ob[r * 5 + 1] = 0.0f; ob[r * 5 + 2] = 0.0f;
            ob[r * 5 + 3] = 0.0f; ob[r * 5 + 4] = 0.0f;
        }
    }
}

extern "C" void kernel_launch(void* const* d_in, const int* in_sizes, int n_in,
                              void* d_out, int out_size, void* d_ws, size_t ws_size,
                              hipStream_t stream) {
    const float* cls  = (const float*)d_in[0];
    const float* reg  = (const float*)d_in[1];
    const float* anch = (const float*)d_in[2];
    float* topS = (float*)d_ws;                              // 32*1024 f32
    float* topB = topS + B_CNT * PRE;                        // 32*1024*4 f32
    u64* masks = (u64*)(topB + (size_t)B_CNT * PRE * 4);     // 32*1024*16 u64

    sel_kernel<<<B_CNT, 1024, 0, stream>>>(cls, reg, anch, topS, topB);
    mask_kernel<<<dim3(16, B_CNT), 1024, 0, stream>>>(topB, masks);
    nms_kernel<<<B_CNT, 64, 0, stream>>>(masks, topS, topB, (float*)d_out);
}